// Round 5
// baseline (68.587 us; speedup 1.0000x reference)
//
#include <hip/hip_runtime.h>
#include <math.h>

#define B_ 4
#define C_ 32
#define H_ 256
#define W_ 256
#define HW_ (H_ * W_)
#define K_ 9
#define TX 32
#define TY 16
#define HX 34              // TX + 2
#define HY 18              // TY + 2
#define HCH (HX * HY)      // 612 floats per channel halo
#define HTOT (HCH * C_)    // 19584 floats = 78.3 KB
#define EPS_ 1e-12f

// 1024 threads = 16 waves; tile 32x16, 2 threads/pixel (channel halves).
// LDS 78.3 KB -> exactly 2 blocks/CU (156.7/160 KB) = 32 waves/CU = 100% occ.
// Grid 512 = exactly 2 blocks/CU: no tail. launch_bounds(1024,8) caps VGPR=64.
// fe kept in 16 regs across softmax (live ~45 < 64: no spill, unlike R2).
__global__ __launch_bounds__(1024, 8) void asfr_kernel(const float* __restrict__ fe,
                                                       const float* __restrict__ fu,
                                                       float* __restrict__ out) {
    __shared__ float smem[HTOT];
    const int t = threadIdx.x;
    const int bx = blockIdx.x & 7;           // W_/TX = 8
    const int by = (blockIdx.x >> 3) & 15;   // H_/TY = 16
    const int b  = blockIdx.x >> 7;
    const int w0 = bx * TX, h0 = by * TY;

    const int x = t & 31;            // pixel x
    const int half = (t >> 5) & 1;   // channel half
    const int y = t >> 6;            // pixel y (wave id)
    const int c0 = half << 4;
    const int pxoff = b * (C_ * HW_) + (h0 + y) * W_ + (w0 + x);

    // fe channel vector (this half) into registers — issued early, overlaps staging
    float fereg[16];
#pragma unroll
    for (int cc = 0; cc < 16; ++cc) fereg[cc] = fe[pxoff + (c0 + cc) * HW_];

    // stage fu halo tile (all 32 channels) into LDS, zero-padded borders
    const float* fub = fu + b * (C_ * HW_);
#pragma unroll 4
    for (int j = 0; j < 19; ++j) {
        int i = t + j * 1024;
        int c = i / HCH;
        int rem = i - c * HCH;
        int r = rem / HX;
        int col = rem - r * HX;
        int hh = h0 - 1 + r;
        int ww = w0 - 1 + col;
        float v = 0.f;
        if (((unsigned)hh < (unsigned)H_) && ((unsigned)ww < (unsigned)W_))
            v = fub[c * HW_ + hh * W_ + ww];
        smem[i] = v;
    }
    {   // tail: i = t + 19*1024, valid for t < 128
        int i = t + 19456;
        if (i < HTOT) {
            int c = i / HCH;
            int rem = i - c * HCH;
            int r = rem / HX;
            int col = rem - r * HX;
            int hh = h0 - 1 + r;
            int ww = w0 - 1 + col;
            float v = 0.f;
            if (((unsigned)hh < (unsigned)H_) && ((unsigned)ww < (unsigned)W_))
                v = fub[c * HW_ + hh * W_ + ww];
            smem[i] = v;
        }
    }
    __syncthreads();

    const int hc = (y + 1) * HX + (x + 1);
    const int koff[K_] = {-HX - 1, -HX, -HX + 1, -1, 0, 1, HX - 1, HX, HX + 1};

    float dot[K_], psq[K_];
#pragma unroll
    for (int k = 0; k < K_; ++k) { dot[k] = 0.f; psq[k] = 0.f; }
    float fsq = 0.f;

    // Pass 1: per-k statistics over this half's 16 channels (fu from LDS)
#pragma unroll 4
    for (int cc = 0; cc < 16; ++cc) {
        float f = fereg[cc];
        fsq = fmaf(f, f, fsq);
        const int sb = (c0 + cc) * HCH + hc;
#pragma unroll
        for (int k = 0; k < K_; ++k) {
            float p = smem[sb + koff[k]];
            dot[k] = fmaf(p, f, dot[k]);
            psq[k] = fmaf(p, p, psq[k]);
        }
    }

    // combine halves: lanes l and l^32 hold the two channel-halves of one pixel
#pragma unroll
    for (int k = 0; k < K_; ++k) {
        dot[k] += __shfl_xor(dot[k], 32);
        psq[k] += __shfl_xor(psq[k], 32);
    }
    fsq += __shfl_xor(fsq, 32);

    float nf = fmaxf(sqrtf(fsq), EPS_);
    float cosv[K_], negd[K_];
#pragma unroll
    for (int k = 0; k < K_; ++k) {
        float np = fmaxf(sqrtf(psq[k]), EPS_);
        cosv[k] = __fdividef(dot[k], np * nf);
        float dsq = fmaxf(psq[k] - 2.f * dot[k] + fsq, 0.f);   // ||p-f||^2
        negd[k] = -sqrtf(dsq);
    }

    float m1 = cosv[0], m2 = negd[0];
#pragma unroll
    for (int k = 1; k < K_; ++k) { m1 = fmaxf(m1, cosv[k]); m2 = fmaxf(m2, negd[k]); }
    float s1 = 0.f, s2 = 0.f, e1[K_], e2[K_];
#pragma unroll
    for (int k = 0; k < K_; ++k) {
        e1[k] = __expf(cosv[k] - m1);
        e2[k] = __expf(negd[k] - m2);
        s1 += e1[k]; s2 += e2[k];
    }
    float r1 = __fdividef(0.5f, s1), r2 = __fdividef(0.5f, s2);
    float wt[K_];
#pragma unroll
    for (int k = 0; k < K_; ++k) wt[k] = fmaf(e1[k], r1, e2[k] * r2);

    // Pass 2: weighted gather from LDS + residual from registers
#pragma unroll 4
    for (int cc = 0; cc < 16; ++cc) {
        const int sb = (c0 + cc) * HCH + hc;
        float acc = fereg[cc];
#pragma unroll
        for (int k = 0; k < K_; ++k) acc = fmaf(wt[k], smem[sb + koff[k]], acc);
        out[pxoff + (c0 + cc) * HW_] = acc;
    }
}

extern "C" void kernel_launch(void* const* d_in, const int* in_sizes, int n_in,
                              void* d_out, int out_size, void* d_ws, size_t ws_size,
                              hipStream_t stream) {
    const float* fe = (const float*)d_in[0];
    const float* fu = (const float*)d_in[1];
    float* out = (float*)d_out;
    dim3 grid((W_ / TX) * (H_ / TY) * B_), block(1024);  // 512 blocks, 2/CU
    hipLaunchKernelGGL(asfr_kernel, grid, block, 0, stream, fe, fu, out);
}

// Round 6
// 39.304 us; speedup vs baseline: 1.7450x; 1.7450x over previous
//
#include <hip/hip_runtime.h>
#include <math.h>

#define B_ 4
#define C_ 32
#define H_ 256
#define W_ 256
#define HW_ (H_ * W_)
#define K_ 9
#define TX 32
#define TY 4
#define HX 34              // TX + 2
#define HY 6               // TY + 2
#define HCH (HX * HY)      // 204 positions per channel-pair halo
#define NPAIR 16           // 32 channels as 16 bf16x2 pairs
#define HWORDS (HCH * NPAIR)   // 3264 words = 12.75 KB
#define EPS_ 1e-12f

// R4 structure (256 thr, 32x4 tile, 2 thr/pixel channel-halves, fe re-read from
// global in both passes -> VGPR ~40, no spill) + bf16-pair LDS staging:
// 12.75 KB/block -> 8 blocks/CU (wave-limited) = 32 waves/CU; grid 2048 = exactly
// 8/CU, no tail. One ds_read_b32 = 2 channels. launch_bounds(256,8): VGPR cap 64.
// Lesson R2/R5: cap must exceed live set (~48) by margin — 64 does, 32/84 didn't.

__device__ __forceinline__ unsigned f2bf(float v) {
    unsigned u = __float_as_uint(v);
    return (u + 0x7FFFu + ((u >> 16) & 1u)) >> 16;   // RNE to bf16
}

__global__ __launch_bounds__(256, 8) void asfr_kernel(const float* __restrict__ fe,
                                                      const float* __restrict__ fu,
                                                      float* __restrict__ out) {
    __shared__ unsigned smem[HWORDS];
    const int t = threadIdx.x;
    const int bx = blockIdx.x & 7;           // W_/TX = 8
    const int by = (blockIdx.x >> 3) & 63;   // H_/TY = 64
    const int b  = blockIdx.x >> 9;
    const int w0 = bx * TX, h0 = by * TY;

    // stage fu halo as packed bf16 pairs: word(pair,pos) = bf16(c=2p) | bf16(c=2p+1)<<16
    const float* fub = fu + b * (C_ * HW_);
#pragma unroll 4
    for (int j = 0; j < 12; ++j) {
        int i = t + j * 256;
        int pair = i / HCH;
        int pos = i - pair * HCH;
        int r = pos / HX;
        int col = pos - r * HX;
        int hh = h0 - 1 + r;
        int ww = w0 - 1 + col;
        unsigned wword = 0u;
        if (((unsigned)hh < (unsigned)H_) && ((unsigned)ww < (unsigned)W_)) {
            const float* p = fub + (2 * pair) * HW_ + hh * W_ + ww;
            wword = f2bf(p[0]) | (f2bf(p[HW_]) << 16);
        }
        smem[i] = wword;
    }
    {   // tail: i = t + 12*256, valid for t < 192
        int i = t + 3072;
        if (i < HWORDS) {
            int pair = i / HCH;
            int pos = i - pair * HCH;
            int r = pos / HX;
            int col = pos - r * HX;
            int hh = h0 - 1 + r;
            int ww = w0 - 1 + col;
            unsigned wword = 0u;
            if (((unsigned)hh < (unsigned)H_) && ((unsigned)ww < (unsigned)W_)) {
                const float* p = fub + (2 * pair) * HW_ + hh * W_ + ww;
                wword = f2bf(p[0]) | (f2bf(p[HW_]) << 16);
            }
            smem[i] = wword;
        }
    }
    __syncthreads();

    const int x = t & 31;            // pixel x
    const int half = (t >> 5) & 1;   // channel half: pairs 0..7 or 8..15
    const int y = t >> 6;            // pixel y (wave id)
    const int p0 = half << 3;        // first pair index
    const int pxoff = b * (C_ * HW_) + (h0 + y) * W_ + (w0 + x);
    const int hc = (y + 1) * HX + (x + 1);
    const int koff[K_] = {-HX - 1, -HX, -HX + 1, -1, 0, 1, HX - 1, HX, HX + 1};

    float dot[K_], psq[K_];
#pragma unroll
    for (int k = 0; k < K_; ++k) { dot[k] = 0.f; psq[k] = 0.f; }
    float fsq = 0.f;

    // Pass 1: per-k statistics over this half's 8 pairs (16 channels)
#pragma unroll 2
    for (int pp = 0; pp < 8; ++pp) {
        const int pr = p0 + pp;
        const float* fp = fe + pxoff + (2 * pr) * HW_;
        float fa = fp[0], fb = fp[HW_];
        fsq = fmaf(fa, fa, fsq);
        fsq = fmaf(fb, fb, fsq);
        const int sb = pr * HCH + hc;
#pragma unroll
        for (int k = 0; k < K_; ++k) {
            unsigned wv = smem[sb + koff[k]];
            float pa = __uint_as_float(wv << 16);
            float pb = __uint_as_float(wv & 0xFFFF0000u);
            dot[k] = fmaf(pa, fa, dot[k]);
            psq[k] = fmaf(pa, pa, psq[k]);
            dot[k] = fmaf(pb, fb, dot[k]);
            psq[k] = fmaf(pb, pb, psq[k]);
        }
    }

    // combine halves: lanes l and l^32 hold the two channel-halves of one pixel
#pragma unroll
    for (int k = 0; k < K_; ++k) {
        dot[k] += __shfl_xor(dot[k], 32);
        psq[k] += __shfl_xor(psq[k], 32);
    }
    fsq += __shfl_xor(fsq, 32);

    float nf = fmaxf(sqrtf(fsq), EPS_);
    float cosv[K_], negd[K_];
#pragma unroll
    for (int k = 0; k < K_; ++k) {
        float np = fmaxf(sqrtf(psq[k]), EPS_);
        cosv[k] = __fdividef(dot[k], np * nf);
        float dsq = fmaxf(psq[k] - 2.f * dot[k] + fsq, 0.f);   // ||p-f||^2
        negd[k] = -sqrtf(dsq);
    }

    float m1 = cosv[0], m2 = negd[0];
#pragma unroll
    for (int k = 1; k < K_; ++k) { m1 = fmaxf(m1, cosv[k]); m2 = fmaxf(m2, negd[k]); }
    float s1 = 0.f, s2 = 0.f, e1[K_], e2[K_];
#pragma unroll
    for (int k = 0; k < K_; ++k) {
        e1[k] = __expf(cosv[k] - m1);
        e2[k] = __expf(negd[k] - m2);
        s1 += e1[k]; s2 += e2[k];
    }
    float r1 = __fdividef(0.5f, s1), r2 = __fdividef(0.5f, s2);
    float wt[K_];
#pragma unroll
    for (int k = 0; k < K_; ++k) wt[k] = fmaf(e1[k], r1, e2[k] * r2);

    // Pass 2: weighted gather from LDS + residual re-read from global (L2-warm)
#pragma unroll 2
    for (int pp = 0; pp < 8; ++pp) {
        const int pr = p0 + pp;
        const float* fp = fe + pxoff + (2 * pr) * HW_;
        float acca = fp[0], accb = fp[HW_];
        const int sb = pr * HCH + hc;
#pragma unroll
        for (int k = 0; k < K_; ++k) {
            unsigned wv = smem[sb + koff[k]];
            float pa = __uint_as_float(wv << 16);
            float pb = __uint_as_float(wv & 0xFFFF0000u);
            acca = fmaf(wt[k], pa, acca);
            accb = fmaf(wt[k], pb, accb);
        }
        float* op = out + pxoff + (2 * pr) * HW_;
        op[0] = acca;
        op[HW_] = accb;
    }
}

extern "C" void kernel_launch(void* const* d_in, const int* in_sizes, int n_in,
                              void* d_out, int out_size, void* d_ws, size_t ws_size,
                              hipStream_t stream) {
    const float* fe = (const float*)d_in[0];
    const float* fu = (const float*)d_in[1];
    float* out = (float*)d_out;
    dim3 grid((W_ / TX) * (H_ / TY) * B_), block(256);  // 2048 blocks = 8/CU exact
    hipLaunchKernelGGL(asfr_kernel, grid, block, 0, stream, fe, fu, out);
}

// Round 7
// 38.233 us; speedup vs baseline: 1.7939x; 1.0280x over previous
//
#include <hip/hip_runtime.h>
#include <math.h>

#define B_ 4
#define C_ 32
#define H_ 256
#define W_ 256
#define HW_ (H_ * W_)
#define K_ 9
#define TX 32
#define TY 4
#define HX 34              // TX + 2
#define HY 6               // TY + 2
#define HCH (HX * HY)      // 204 positions per channel-pair halo
#define NPAIR 16           // 32 channels as 16 f16x2 pairs
#define HWORDS (HCH * NPAIR)   // 3264 words = 12.75 KB
#define EPS_ 1e-12f

typedef _Float16 h2v __attribute__((ext_vector_type(2)));

// R6 structure (256 thr, 32x4 tile, 2 thr/pixel channel-halves, fe from global
// both passes, 12.75 KB LDS -> 8 blocks/CU, grid 2048 = exact fill) with taps
// switched bf16->f16 pairs and per-tap math in packed v_pk_fma_f16:
// pass1 word-k = 2 packed FMAs (was 6 ops), pass2 word-k = 1 (was 4).
// f16 accumulation: |dot|,|psq| << 65504, rel err ~1e-3 -> output ~0.02 << 0.12.
// VGPR lesson (R2/R5): cap 64 via launch_bounds(256,8), live set ~44.
__global__ __launch_bounds__(256, 8) void asfr_kernel(const float* __restrict__ fe,
                                                      const float* __restrict__ fu,
                                                      float* __restrict__ out) {
    __shared__ h2v smem[HWORDS];
    const int t = threadIdx.x;
    const int bx = blockIdx.x & 7;           // W_/TX = 8
    const int by = (blockIdx.x >> 3) & 63;   // H_/TY = 64
    const int b  = blockIdx.x >> 9;
    const int w0 = bx * TX, h0 = by * TY;

    // stage fu halo as packed f16 pairs: word(pair,pos) = (f16(c=2p), f16(c=2p+1))
    const float* fub = fu + b * (C_ * HW_);
#pragma unroll 4
    for (int j = 0; j < 12; ++j) {
        int i = t + j * 256;
        int pair = i / HCH;
        int pos = i - pair * HCH;
        int r = pos / HX;
        int col = pos - r * HX;
        int hh = h0 - 1 + r;
        int ww = w0 - 1 + col;
        float a = 0.f, bb = 0.f;
        if (((unsigned)hh < (unsigned)H_) && ((unsigned)ww < (unsigned)W_)) {
            const float* p = fub + (2 * pair) * HW_ + hh * W_ + ww;
            a = p[0]; bb = p[HW_];
        }
        h2v v = {(_Float16)a, (_Float16)bb};
        smem[i] = v;
    }
    {   // tail: i = t + 12*256, valid for t < 192
        int i = t + 3072;
        if (i < HWORDS) {
            int pair = i / HCH;
            int pos = i - pair * HCH;
            int r = pos / HX;
            int col = pos - r * HX;
            int hh = h0 - 1 + r;
            int ww = w0 - 1 + col;
            float a = 0.f, bb = 0.f;
            if (((unsigned)hh < (unsigned)H_) && ((unsigned)ww < (unsigned)W_)) {
                const float* p = fub + (2 * pair) * HW_ + hh * W_ + ww;
                a = p[0]; bb = p[HW_];
            }
            h2v v = {(_Float16)a, (_Float16)bb};
            smem[i] = v;
        }
    }
    __syncthreads();

    const int x = t & 31;            // pixel x
    const int half = (t >> 5) & 1;   // channel half: pairs 0..7 or 8..15
    const int y = t >> 6;            // pixel y (wave id)
    const int p0 = half << 3;        // first pair index
    const int pxoff = b * (C_ * HW_) + (h0 + y) * W_ + (w0 + x);
    const int hc = (y + 1) * HX + (x + 1);
    const int koff[K_] = {-HX - 1, -HX, -HX + 1, -1, 0, 1, HX - 1, HX, HX + 1};

    h2v da[K_], qa[K_];
    const h2v zz = {(_Float16)0, (_Float16)0};
#pragma unroll
    for (int k = 0; k < K_; ++k) { da[k] = zz; qa[k] = zz; }
    float fsq = 0.f;

    // Pass 1: packed per-k statistics over this half's 8 pairs (16 channels)
#pragma unroll 4
    for (int pp = 0; pp < 8; ++pp) {
        const int pr = p0 + pp;
        const float* fp = fe + pxoff + (2 * pr) * HW_;
        float fa = fp[0], fb = fp[HW_];
        fsq = fmaf(fa, fa, fmaf(fb, fb, fsq));
        h2v fe2 = {(_Float16)fa, (_Float16)fb};
        const int sb = pr * HCH + hc;
#pragma unroll
        for (int k = 0; k < K_; ++k) {
            h2v p = smem[sb + koff[k]];
            da[k] += p * fe2;   // v_pk_fma_f16
            qa[k] += p * p;     // v_pk_fma_f16
        }
    }

    // unpack to f32, combine the two channel-halves (lanes l and l^32)
    float dot[K_], psq[K_];
#pragma unroll
    for (int k = 0; k < K_; ++k) {
        dot[k] = (float)da[k][0] + (float)da[k][1];
        psq[k] = (float)qa[k][0] + (float)qa[k][1];
        dot[k] += __shfl_xor(dot[k], 32);
        psq[k] += __shfl_xor(psq[k], 32);
    }
    fsq += __shfl_xor(fsq, 32);

    float nf = fmaxf(sqrtf(fsq), EPS_);
    float cosv[K_], negd[K_];
#pragma unroll
    for (int k = 0; k < K_; ++k) {
        float np = fmaxf(sqrtf(psq[k]), EPS_);
        cosv[k] = __fdividef(dot[k], np * nf);
        float dsq = fmaxf(psq[k] - 2.f * dot[k] + fsq, 0.f);   // ||p-f||^2
        negd[k] = -sqrtf(dsq);
    }

    float m1 = cosv[0], m2 = negd[0];
#pragma unroll
    for (int k = 1; k < K_; ++k) { m1 = fmaxf(m1, cosv[k]); m2 = fmaxf(m2, negd[k]); }
    float s1 = 0.f, s2 = 0.f, e1[K_], e2[K_];
#pragma unroll
    for (int k = 0; k < K_; ++k) {
        e1[k] = __expf(cosv[k] - m1);
        e2[k] = __expf(negd[k] - m2);
        s1 += e1[k]; s2 += e2[k];
    }
    float r1 = __fdividef(0.5f, s1), r2 = __fdividef(0.5f, s2);
    h2v w2[K_];
#pragma unroll
    for (int k = 0; k < K_; ++k) {
        float wk = fmaf(e1[k], r1, e2[k] * r2);
        _Float16 wh = (_Float16)wk;
        h2v tmp = {wh, wh};
        w2[k] = tmp;
    }

    // Pass 2: packed weighted gather + fp32 residual
#pragma unroll 2
    for (int pp = 0; pp < 8; ++pp) {
        const int pr = p0 + pp;
        const int sb = pr * HCH + hc;
        h2v acc = zz;
#pragma unroll
        for (int k = 0; k < K_; ++k) acc += w2[k] * smem[sb + koff[k]];  // v_pk_fma_f16
        const float* fp = fe + pxoff + (2 * pr) * HW_;
        float* op = out + pxoff + (2 * pr) * HW_;
        op[0]   = fp[0]   + (float)acc[0];
        op[HW_] = fp[HW_] + (float)acc[1];
    }
}

extern "C" void kernel_launch(void* const* d_in, const int* in_sizes, int n_in,
                              void* d_out, int out_size, void* d_ws, size_t ws_size,
                              hipStream_t stream) {
    const float* fe = (const float*)d_in[0];
    const float* fu = (const float*)d_in[1];
    float* out = (float*)d_out;
    dim3 grid((W_ / TX) * (H_ / TY) * B_), block(256);  // 2048 blocks = 8/CU exact
    hipLaunchKernelGGL(asfr_kernel, grid, block, 0, stream, fe, fu, out);
}